// Round 1
// 165.865 us; speedup vs baseline: 1.0048x; 1.0048x over previous
//
#include <hip/hip_runtime.h>

// B=16, T=1024, N=1024, D=256, WIN=64
// outputs (flat): R (B,T,2D) = [A@V, Q]   : 8388608 f32
//                 alignments (B,N,T) = A^T: 16777216 f32
//                 max_att (B,T)           : 16384 f32
//
// v8: fuse zero_nonwin into the attention kernel (single launch).
//  - v7 serialized zero_nonwin (~13 us pure HBM-write) behind attn (~36 us,
//    VALU/L2-bound in PV). Their pipes are complementary, so the 63 MB of
//    zero-writes can hide under PV compute.
//  - Each block (1024 = 16 batches x 64 chunks) zeroes its own 15 non-window
//    alignment rows. Stores are issued AFTER the last __syncthreads (barriers
//    emit a full vmcnt(0) drain) and BEFORE the PV loop, so the drain overlaps
//    PV's V-loads/FMAs and the R-write phase.
//  - Window rows (prev..prev+63) are written only by the strip store; zeroed
//    rows are disjoint by construction. Every aligns row written exactly once.

#define BB 16
#define TT 1024
#define NN 1024
#define DD 256
#define WIN 64
#define TBLK 16          // queries per block
#define NT 256           // 4 waves, 4 queries each

#define R_ELEMS   (16u*1024u*512u)        // 8388608
#define ALN_ELEMS (16u*1024u*1024u)       // 16777216

#define LSTR 132         // LDS row stride (dwords); 132%32==4 -> conflict-free b128

__global__ __launch_bounds__(NT, 4) void attn_v8(
    const float* __restrict__ Q, const float* __restrict__ K,
    const float* __restrict__ V, const int* __restrict__ prev_in,
    float* __restrict__ out)
{
    __shared__ float ks[WIN * LSTR];        // 33792 B: K half-tile
    __shared__ float p_lds[TBLK][WIN + 4];  // 4352 B : probabilities [t][j]

    float* Rout   = out;
    float* aligns = out + R_ELEMS;
    float* maxatt = out + R_ELEMS + ALN_ELEMS;

    const int tid  = threadIdx.x;
    const int lane = tid & 63;
    const int w    = __builtin_amdgcn_readfirstlane(tid >> 6);  // wave 0..3 (uniform)
    const int b    = blockIdx.x >> 6;       // 64 blocks per batch
    const int t0   = (blockIdx.x & 63) * TBLK;
    const int prev = prev_in[b];

    const float* qb = Q + ((size_t)b * TT + t0 + 4 * w) * DD;   // scalar base

    // ================= QK^T over two 128-d halves =================
    float acc[4] = {0.f, 0.f, 0.f, 0.f};
    #pragma unroll
    for (int h = 0; h < 2; ++h) {
        if (h) __syncthreads();             // h0 readers done before restage
        const float4* Ksrc = (const float4*)(K + ((size_t)b * NN + prev) * DD + h * 128);
        #pragma unroll
        for (int k = 0; k < 8; ++k) {
            int t4 = tid + k * NT;          // 0..2047 float4 chunks
            int r = t4 >> 5, c = t4 & 31;
            float4 v = Ksrc[(size_t)r * 64 + c];
            *(float4*)&ks[r * LSTR + c * 4] = v;
        }
        __syncthreads();

        const float* qh = qb + h * 128;
        #pragma unroll 8
        for (int d4 = 0; d4 < 32; ++d4) {
            float4 kk = *(const float4*)&ks[lane * LSTR + d4 * 4];  // conflict-free b128
            #pragma unroll
            for (int t = 0; t < 4; ++t) {
                float4 q = ((const float4*)(qh + t * DD))[d4];      // wave-uniform
                acc[t] = fmaf(q.x, kk.x, fmaf(q.y, kk.y, fmaf(q.z, kk.z, fmaf(q.w, kk.w, acc[t]))));
            }
        }
    }

    // ================= softmax + argmax (wave-local), p -> LDS ===========
    #pragma unroll
    for (int t = 0; t < 4; ++t) {
        float v = acc[t] * 0.0625f;         // 1/sqrt(256)

        float m = v;
        #pragma unroll
        for (int off = 32; off; off >>= 1) m = fmaxf(m, __shfl_xor(m, off));

        float e = expf(v - m);
        float s = e;
        #pragma unroll
        for (int off = 32; off; off >>= 1) s += __shfl_xor(s, off);

        p_lds[4 * w + t][lane] = e / s;

        float av = v; int ai = lane;
        #pragma unroll
        for (int off = 32; off; off >>= 1) {
            float ov = __shfl_xor(av, off);
            int   oi = __shfl_xor(ai, off);
            if (ov > av || (ov == av && oi < ai)) { av = ov; ai = oi; }
        }
        if (lane == 0) maxatt[(size_t)b * TT + t0 + 4 * w + t] = (float)(prev + ai);
    }
    __syncthreads();                        // all 16 p rows visible (last barrier)

    // ===== window-row alignment strip: 64 rows x 16 floats (64B lines) ====
    {
        const int j = tid >> 2, cg = tid & 3;
        float4 v;
        v.x = p_lds[cg * 4 + 0][j];
        v.y = p_lds[cg * 4 + 1][j];
        v.z = p_lds[cg * 4 + 2][j];
        v.w = p_lds[cg * 4 + 3][j];
        *(float4*)(aligns + ((size_t)b * NN + prev + j) * TT + t0 + cg * 4) = v;
    }

    // ===== fused zeroing of this block's 15 non-window alignment rows =====
    // Issued after the last barrier (no vmcnt(0) drain ahead), before PV so
    // the ~60KB/block store drain hides under PV's L2 loads + FMAs.
    {
        const int chunk = blockIdx.x & 63;
        float4* zbase = (float4*)(aligns + (size_t)b * NN * TT);
        const float4 z = make_float4(0.f, 0.f, 0.f, 0.f);
        #pragma unroll
        for (int r = 0; r < 15; ++r) {
            int idx = chunk * 15 + r;          // 0..959 among non-window rows
            int n   = idx < prev ? idx : idx + WIN;
            zbase[(size_t)n * 256 + tid] = z;  // 4KB contiguous per store-row
        }
    }

    // ================= PV direct from global (L2-hot V) ==================
    // lane = d-chunk (64 x float4 = 256 d); reads own wave's p rows.
    {
        const float4* V4 = (const float4*)(V + ((size_t)b * NN + prev) * DD);
        float4 o[4];
        #pragma unroll
        for (int t = 0; t < 4; ++t) o[t] = make_float4(0.f, 0.f, 0.f, 0.f);

        #pragma unroll 4
        for (int j4 = 0; j4 < WIN / 4; ++j4) {
            float4 p0 = *(const float4*)&p_lds[4 * w + 0][j4 * 4];  // uniform bcast
            float4 p1 = *(const float4*)&p_lds[4 * w + 1][j4 * 4];
            float4 p2 = *(const float4*)&p_lds[4 * w + 2][j4 * 4];
            float4 p3 = *(const float4*)&p_lds[4 * w + 3][j4 * 4];
            float4 v0 = V4[(size_t)(j4 * 4 + 0) * 64 + lane];
            float4 v1 = V4[(size_t)(j4 * 4 + 1) * 64 + lane];
            float4 v2 = V4[(size_t)(j4 * 4 + 2) * 64 + lane];
            float4 v3 = V4[(size_t)(j4 * 4 + 3) * 64 + lane];
            #define ACC4(o_, p_) \
                o_.x = fmaf(p_.x, v0.x, fmaf(p_.y, v1.x, fmaf(p_.z, v2.x, fmaf(p_.w, v3.x, o_.x)))); \
                o_.y = fmaf(p_.x, v0.y, fmaf(p_.y, v1.y, fmaf(p_.z, v2.y, fmaf(p_.w, v3.y, o_.y)))); \
                o_.z = fmaf(p_.x, v0.z, fmaf(p_.y, v1.z, fmaf(p_.z, v2.z, fmaf(p_.w, v3.z, o_.z)))); \
                o_.w = fmaf(p_.x, v0.w, fmaf(p_.y, v1.w, fmaf(p_.z, v2.w, fmaf(p_.w, v3.w, o_.w))));
            ACC4(o[0], p0) ACC4(o[1], p1) ACC4(o[2], p2) ACC4(o[3], p3)
            #undef ACC4
        }

        #pragma unroll
        for (int t = 0; t < 4; ++t) {
            float* Rrow = Rout + ((size_t)b * TT + t0 + 4 * w + t) * (2 * DD);
            ((float4*)Rrow)[lane] = o[t];                               // A@V
            ((float4*)(Rrow + DD))[lane] = ((const float4*)(qb + t * DD))[lane];  // Q copy
        }
    }
}

extern "C" void kernel_launch(void* const* d_in, const int* in_sizes, int n_in,
                              void* d_out, int out_size, void* d_ws, size_t ws_size,
                              hipStream_t stream) {
    const float* Q = (const float*)d_in[0];
    const float* K = (const float*)d_in[1];
    const float* V = (const float*)d_in[2];
    const int* prev = (const int*)d_in[3];
    float* out = (float*)d_out;

    // single fused launch: R, maxatt, window strip, AND non-window zeroing
    attn_v8<<<BB * TT / TBLK, NT, 0, stream>>>(Q, K, V, prev, out);
}